// Round 5
// baseline (286.890 us; speedup 1.0000x reference)
//
#include <hip/hip_runtime.h>
#include <hip/hip_bf16.h>
#include <stdint.h>

// BOXLoss: N=1e6 rows, G=32 groups. Output = scalar loss.
// Pass B: read is_in_boxes (128MB) once -> pack to 1 bit/entry (4MB in ws) +
//         per-column conf[g] = max masked score (atomicMax on float-as-uint, vals >= 0).
// Pass C: mx[g] = max masked scores[i]^conf[g] * iou[i]   (reads ~12MB)
// Pass D: accumulate focal-loss terms, /= num_pos_avg     (reads ~16MB)

constexpr float kClamp = 1e-4f;

__global__ void init_kernel(uint32_t* confbits, uint32_t* mxbits, float* out) {
    int t = threadIdx.x;
    if (t < 32) { confbits[t] = 0u; mxbits[t] = 0u; }
    if (t == 0) out[0] = 0.0f;
}

// Each lane handles one int4 (4 group entries). 8 lanes = 1 row (G=32).
// Lanes are grouped 8-aligned (blockDim & grid stride are multiples of 256).
template <bool WRITE_BITS>
__global__ void pack_conf_kernel(const int4* __restrict__ boxes4,
                                 const float* __restrict__ scores,
                                 uint32_t* __restrict__ bits,
                                 uint32_t* __restrict__ confbits,
                                 long long nchunks) {
    __shared__ uint32_t conf_lds[32];
    int tid = threadIdx.x;
    if (tid < 32) conf_lds[tid] = 0u;
    __syncthreads();
    long long stride = (long long)gridDim.x * blockDim.x;
    for (long long c = (long long)blockIdx.x * blockDim.x + tid; c < nchunks; c += stride) {
        int4 v = boxes4[c];
        uint32_t nib = (uint32_t)(v.x > 0) | ((uint32_t)(v.y > 0) << 1) |
                       ((uint32_t)(v.z > 0) << 2) | ((uint32_t)(v.w > 0) << 3);
        int sub = (int)(c & 7);                 // which nibble of the row
        long long row = c >> 3;
        if (WRITE_BITS) {
            uint32_t r = nib << (sub * 4);
            r |= __shfl_xor(r, 1);
            r |= __shfl_xor(r, 2);
            r |= __shfl_xor(r, 4);              // 8-lane OR -> full row mask
            if ((tid & 7) == 0) bits[row] = r;  // always write (ws is poisoned)
        }
        if (nib) {
            uint32_t sb = __float_as_uint(scores[row]);  // scores >= 0
            int g0 = sub * 4;
            if (nib & 1u) atomicMax(&conf_lds[g0 + 0], sb);
            if (nib & 2u) atomicMax(&conf_lds[g0 + 1], sb);
            if (nib & 4u) atomicMax(&conf_lds[g0 + 2], sb);
            if (nib & 8u) atomicMax(&conf_lds[g0 + 3], sb);
        }
    }
    __syncthreads();
    if (tid < 32 && conf_lds[tid]) atomicMax(&confbits[tid], conf_lds[tid]);
}

__device__ inline uint32_t row_mask_from_boxes(const int4* __restrict__ boxes4, int row) {
    uint32_t m = 0;
#pragma unroll
    for (int k = 0; k < 8; ++k) {
        int4 v = boxes4[(long long)row * 8 + k];
        uint32_t nib = (uint32_t)(v.x > 0) | ((uint32_t)(v.y > 0) << 1) |
                       ((uint32_t)(v.z > 0) << 2) | ((uint32_t)(v.w > 0) << 3);
        m |= nib << (k * 4);
    }
    return m;
}

template <bool USE_BITS>
__global__ void mx_kernel(const uint32_t* __restrict__ bits,
                          const int4* __restrict__ boxes4,
                          const float* __restrict__ scores,
                          const float* __restrict__ iouMap,
                          const uint32_t* __restrict__ confbits,
                          uint32_t* __restrict__ mxbits, int n) {
    __shared__ float conf_lds[32];
    __shared__ uint32_t mx_lds[32];
    int tid = threadIdx.x;
    if (tid < 32) { conf_lds[tid] = __uint_as_float(confbits[tid]); mx_lds[tid] = 0u; }
    __syncthreads();
    int stride = gridDim.x * blockDim.x;
    for (int row = blockIdx.x * blockDim.x + tid; row < n; row += stride) {
        uint32_t m = USE_BITS ? bits[row] : row_mask_from_boxes(boxes4, row);
        if (!m) continue;
        float s = scores[row];
        float iou = iouMap[row];
        float l2s = log2f(s);                   // -inf for s==0
        while (m) {
            int g = __ffs(m) - 1;
            m &= m - 1;
            float t = conf_lds[g] * l2s;
            float e = exp2f(t);
            if (t != t) e = 1.0f;               // pow(0,0) == 1
            float raw = e * iou;                // >= 0
            atomicMax(&mx_lds[g], __float_as_uint(raw));
        }
    }
    __syncthreads();
    if (tid < 32 && mx_lds[tid]) atomicMax(&mxbits[tid], mx_lds[tid]);
}

template <bool USE_BITS>
__global__ void loss_kernel(const uint32_t* __restrict__ bits,
                            const int4* __restrict__ boxes4,
                            const float* __restrict__ logits,
                            const float* __restrict__ scores,
                            const float* __restrict__ iouMap,
                            const uint32_t* __restrict__ confbits,
                            const uint32_t* __restrict__ mxbits,
                            const void* __restrict__ denom_ptr,
                            float* __restrict__ out, int n) {
    __shared__ float conf_lds[32];
    __shared__ float mx_lds[32];
    __shared__ float wsum[4];
    int tid = threadIdx.x;
    if (tid < 32) {
        conf_lds[tid] = __uint_as_float(confbits[tid]);
        mx_lds[tid] = __uint_as_float(mxbits[tid]);
    }
    __syncthreads();
    float acc = 0.0f;
    int stride = gridDim.x * blockDim.x;
    for (int row = blockIdx.x * blockDim.x + tid; row < n; row += stride) {
        uint32_t m = USE_BITS ? bits[row] : row_mask_from_boxes(boxes4, row);
        float x = logits[row];
        float p = 1.0f / (1.0f + expf(-x));
        p = fminf(fmaxf(p, kClamp), 1.0f - kClamp);
        if (!m) {
            float l1mp = logf(1.0f - p);
            acc -= l1mp * p * p * 0.75f;        // (1 - FOCAL_ALPHA) = 0.75
            continue;
        }
        float s = scores[row];
        float iou = iouMap[row];
        float l2s = log2f(s);
        float logp = logf(p);
        float log1mp = logf(1.0f - p);
        float omp = 1.0f - p;
        while (m) {
            int g = __ffs(m) - 1;
            m &= m - 1;
            float t = conf_lds[g] * l2s;
            float e = exp2f(t);
            if (t != t) e = 1.0f;
            float raw = e * iou;
            float wc = (raw + kClamp) / (mx_lds[g] + kClamp);
            wc = fminf(fmaxf(wc, kClamp), 1.0f - kClamp);
            float a1 = wc * omp;                // pos: -logp * (wc*(1-p))^2
            float a2 = (1.0f - wc) * p;         // boxneg: -log1mp * ((1-wc)*p)^2
            acc -= (logp * a1 * a1 + log1mp * a2 * a2) * 0.25f;  // FOCAL_ALPHA
        }
    }
    // block reduction: wave shuffle, then 4 wave sums, one atomicAdd per block
    for (int off = 32; off > 0; off >>= 1) acc += __shfl_down(acc, off);
    if ((tid & 63) == 0) wsum[tid >> 6] = acc;
    __syncthreads();
    if (tid == 0) {
        int iv = *(const int*)denom_ptr;        // num_pos_avg: int or float bits
        float fv = *(const float*)denom_ptr;
        float denom = (iv > 0 && iv < (1 << 24)) ? (float)iv : fv;
        float tot = (wsum[0] + wsum[1] + wsum[2] + wsum[3]) / denom;
        atomicAdd(out, tot);
    }
}

extern "C" void kernel_launch(void* const* d_in, const int* in_sizes, int n_in,
                              void* d_out, int out_size, void* d_ws, size_t ws_size,
                              hipStream_t stream) {
    const float* logits = (const float*)d_in[0];
    const float* scores = (const float*)d_in[1];
    const float* iou    = (const float*)d_in[2];
    const int4*  boxes4 = (const int4*)d_in[3];
    const void*  npa    = d_in[4];
    float* out = (float*)d_out;

    int n = in_sizes[0];                       // 1e6 rows
    long long gtotal = in_sizes[3];            // n * 32
    long long nchunks = gtotal / 4;            // int4 chunks

    uint32_t* confbits = (uint32_t*)d_ws;      // [0..31]
    uint32_t* mxbits   = confbits + 32;        // [32..63]
    uint32_t* bits     = confbits + 64;        // +256B, n uint32
    bool use_bits = ws_size >= (size_t)n * 4 + 256;

    init_kernel<<<1, 64, 0, stream>>>(confbits, mxbits, out);

    if (use_bits)
        pack_conf_kernel<true><<<2048, 256, 0, stream>>>(boxes4, scores, bits, confbits, nchunks);
    else
        pack_conf_kernel<false><<<2048, 256, 0, stream>>>(boxes4, scores, nullptr, confbits, nchunks);

    if (use_bits) {
        mx_kernel<true><<<2048, 256, 0, stream>>>(bits, nullptr, scores, iou, confbits, mxbits, n);
        loss_kernel<true><<<2048, 256, 0, stream>>>(bits, nullptr, logits, scores, iou,
                                                    confbits, mxbits, npa, out, n);
    } else {
        mx_kernel<false><<<2048, 256, 0, stream>>>(nullptr, boxes4, scores, iou, confbits, mxbits, n);
        loss_kernel<false><<<2048, 256, 0, stream>>>(nullptr, boxes4, logits, scores, iou,
                                                     confbits, mxbits, npa, out, n);
    }
}